// Round 7
// baseline (157.414 us; speedup 1.0000x reference)
//
#include <hip/hip_runtime.h>
#include <hip/hip_fp16.h>

#define HID 512
#define GC  640
#define CC  320
#define GG  2
#define DHALF 128
#define MARGIN 0.004f
#define FB 4

typedef __attribute__((ext_vector_type(8))) _Float16 half8;
typedef __attribute__((ext_vector_type(4))) float float4v;

__device__ __forceinline__ void gload16(const void* g, void* l) {
    __builtin_amdgcn_global_load_lds(
        (const __attribute__((address_space(1))) void*)(unsigned long long)g,
        (__attribute__((address_space(3))) void*)(unsigned)(unsigned long long)l,
        16, 0, 0);
}

__global__ __launch_bounds__(256) void zero_misc(float* meanAcc, int* cnt) {
    for (int i = threadIdx.x; i < GC; i += 256) meanAcc[i] = 0.f;
    if (threadIdx.x < 2) cnt[threadIdx.x] = 0;
}

__global__ __launch_bounds__(256) void convert_f16(
    const float* __restrict__ in, unsigned short* __restrict__ out, int n8)
{
    int i = blockIdx.x * 256 + threadIdx.x;
    if (i >= n8) return;
    const float4* p = (const float4*)in + (size_t)i * 2;
    float4 v0 = p[0], v1 = p[1];
    float f[8] = {v0.x, v0.y, v0.z, v0.w, v1.x, v1.y, v1.z, v1.w};
    unsigned r[4];
#pragma unroll
    for (int j = 0; j < 4; ++j) {
        __half2 hh = __float22half2_rn(make_float2(f[2*j], f[2*j+1]));
        r[j] = __builtin_bit_cast(unsigned, hh);
    }
    uint4 o = {r[0], r[1], r[2], r[3]};
    *(uint4*)(out + (size_t)i * 8) = o;
}

// Fused: GEMM (fp16 MFMA, x converted in-register) + softmax-mean + argmax + gather.
// Block: 128 tokens x 320 codes (one group). 8 waves, each owns 16 rows x 320 cols.
// Bs double-buffered, [4 kchunk][320 row][8 half] layout (2-way bank alias = free).
// One barrier per K-step; next-step loads issued before current MFMA burst.
__global__ __launch_bounds__(512, 4) void fused(
    const float* __restrict__ X, const unsigned short* __restrict__ Wh,
    const float* __restrict__ bq, const float* __restrict__ gum,
    const float* __restrict__ cv, float* __restrict__ out,
    float* __restrict__ meanAcc, int* __restrict__ cnt,
    int* __restrict__ flags0, int* __restrict__ flags1)
{
    __shared__ __align__(16) unsigned short Bs[2][10240];   // 2 x 20 KB
    __shared__ float bqs[CC];
    __shared__ float smean[CC];

    const int tid  = threadIdx.x;
    const int lane = tid & 63;
    const int wid  = tid >> 6;          // 0..7
    const int lq   = lane & 15;
    const int q    = lane >> 4;

    // XCD-aware swizzle: (tok,g=0)/(tok,g=1) pairs land on the same XCD
    int bid = blockIdx.x;
    int nwg = gridDim.x;
    int swz = ((nwg & 7) == 0) ? (bid & 7) * (nwg >> 3) + (bid >> 3) : bid;
    const int g    = swz & 1;
    const int tok0 = (swz >> 1) * 128;
    int* flagsg = g ? flags1 : flags0;

    for (int i = tid; i < CC; i += 512) { bqs[i] = bq[g * CC + i]; smean[i] = 0.f; }

    // Per-lane Bs staging sources: 20 wave-issues cover 1280 16B-chunks.
    // issue iss, lane l -> chunk m = iss*64+l; m = qc*320 + row.
    const int iss0 = wid, iss1 = wid + 8, iss2 = wid + 16;   // iss2 only wid<4
    const int m0 = iss0 * 64 + lane, m1 = iss1 * 64 + lane, m2 = iss2 * 64 + lane;
    const int qc0 = m0 / 320, r0 = m0 - qc0 * 320;
    const int qc1 = m1 / 320, r1 = m1 - qc1 * 320;
    const int qc2 = m2 / 320, r2 = m2 - qc2 * 320;
    const unsigned short* srcB0 = Wh + ((size_t)(g * CC + r0)) * HID + qc0 * 8;
    const unsigned short* srcB1 = Wh + ((size_t)(g * CC + r1)) * HID + qc1 * 8;
    const unsigned short* srcB2 = Wh + ((size_t)(g * CC + r2)) * HID + qc2 * 8;

    // x source: lane's row = wid*16+lq, k-chunk = q
    const float* xsrc = X + (size_t)(tok0 + wid * 16 + lq) * HID + q * 8;

    float4v acc[20];
#pragma unroll
    for (int j = 0; j < 20; ++j) acc[j] = (float4v){0.f, 0.f, 0.f, 0.f};

    // prologue: stage k=0 into buf 0; load first x regs
    gload16(srcB0, &Bs[0][iss0 * 512]);
    gload16(srcB1, &Bs[0][iss1 * 512]);
    if (wid < 4) gload16(srcB2, &Bs[0][iss2 * 512]);
    float4 xa = *(const float4*)xsrc;
    float4 xb = *(const float4*)(xsrc + 4);
    __syncthreads();

    int cur = 0;
    for (int kk = 0; kk < 16; ++kk) {
        float4 nxa, nxb;
        if (kk < 15) {
            const int k0n = (kk + 1) * 32;
            gload16(srcB0 + k0n, &Bs[cur ^ 1][iss0 * 512]);
            gload16(srcB1 + k0n, &Bs[cur ^ 1][iss1 * 512]);
            if (wid < 4) gload16(srcB2 + k0n, &Bs[cur ^ 1][iss2 * 512]);
            nxa = *(const float4*)(xsrc + k0n);
            nxb = *(const float4*)(xsrc + k0n + 4);
        }
        half8 a;
        a[0] = (_Float16)xa.x; a[1] = (_Float16)xa.y;
        a[2] = (_Float16)xa.z; a[3] = (_Float16)xa.w;
        a[4] = (_Float16)xb.x; a[5] = (_Float16)xb.y;
        a[6] = (_Float16)xb.z; a[7] = (_Float16)xb.w;
        const unsigned short* bbase = &Bs[cur][(q * 320 + lq) * 8];
#pragma unroll
        for (int j = 0; j < 20; ++j) {
            half8 b = *(const half8*)(bbase + j * 128);
            acc[j] = __builtin_amdgcn_mfma_f32_16x16x32_f16(a, b, acc[j], 0, 0, 0);
        }
        __syncthreads();      // drains vmcnt: Bs[cur^1] + next x complete
        if (kk < 15) { xa = nxa; xb = nxb; }
        cur ^= 1;
    }

    // Epilogue: per reg r, q-group owns row = wid*16 + q*4 + r;
    // lane lq holds cols c = j*16+lq (ascending j => ascending c, tie -> lowest).
    float macc[20];
#pragma unroll
    for (int j = 0; j < 20; ++j) macc[j] = 0.f;

#pragma unroll
    for (int r = 0; r < 4; ++r) {
        const int rowL  = wid * 16 + q * 4 + r;
        const int tglob = tok0 + rowL;
        const float* grow = gum + ((size_t)tglob * GG + g) * CC;
        float le[20];
        float s = 0.f;
        float b = -3.0e38f; int bi = 0; float s2 = -3.0e38f;
#pragma unroll
        for (int j = 0; j < 20; ++j) {
            const int c = j * 16 + lq;
            float lg = acc[j][r] + bqs[c];
            float v  = lg + grow[c];
            if (v > b)       { s2 = b; b = v; bi = c; }
            else if (v > s2) { s2 = v; }
            le[j] = __expf(lg); s += le[j];
        }
        // fused 4-step reduce within the 16-lane group: sum + (max, idx, second)
#pragma unroll
        for (int m = 1; m < 16; m <<= 1) {
            float os  = __shfl_xor(s,  m, 64);
            float ob  = __shfl_xor(b,  m, 64);
            int   obi = __shfl_xor(bi, m, 64);
            float os2 = __shfl_xor(s2, m, 64);
            s += os;
            if (ob > b || (ob == b && obi < bi)) { s2 = fmaxf(os2, b); b = ob; bi = obi; }
            else                                 { s2 = fmaxf(s2, ob); }
        }
        float inv = 1.f / s;
#pragma unroll
        for (int j = 0; j < 20; ++j) macc[j] += le[j] * inv;

        if (lq == 0 && (b - s2) < MARGIN) {
            int p = atomicAdd(&cnt[g], 1);
            flagsg[p] = tglob;
        }
        // gather selected codevector: 16 lanes x 8 floats, coalesced
        const float* cvp = cv + ((size_t)(g * CC + bi)) * DHALF + lq * 8;
        float4 c0v = *(const float4*)cvp;
        float4 c1v = *(const float4*)(cvp + 4);
        float* op = out + (size_t)tglob * 256 + g * DHALF + lq * 8;
        *(float4*)op       = c0v;
        *(float4*)(op + 4) = c1v;
    }
    // fold across q-groups (same cols), then 16 lanes -> LDS, then global
#pragma unroll
    for (int j = 0; j < 20; ++j) {
        macc[j] += __shfl_xor(macc[j], 16, 64);
        macc[j] += __shfl_xor(macc[j], 32, 64);
    }
    if (lane < 16) {
#pragma unroll
        for (int j = 0; j < 20; ++j)
            atomicAdd(&smean[j * 16 + lq], macc[j]);
    }
    __syncthreads();
    for (int i = tid; i < CC; i += 512)
        atomicAdd(&meanAcc[g * CC + i], smean[i]);
}

// Exact fp32 recompute for flagged rows: FB rows share one W pass.
__global__ __launch_bounds__(320) void fixup(
    const float* __restrict__ X, const float* __restrict__ W,
    const float* __restrict__ bq, const float* __restrict__ gum,
    const float* __restrict__ cv, float* __restrict__ out,
    const int* __restrict__ flags0, const int* __restrict__ flags1,
    const int* __restrict__ cnt)
{
    __shared__ float xs[FB][HID];
    __shared__ float vals[FB][CC];
    __shared__ int stok[FB];
    const int tid = threadIdx.x;
    const int n0 = cnt[0], n1 = cnt[1];
    const int nb0 = (n0 + FB - 1) / FB;
    const int nb1 = (n1 + FB - 1) / FB;

    for (int bb = blockIdx.x; bb < nb0 + nb1; bb += gridDim.x) {
        const int g    = (bb < nb0) ? 0 : 1;
        const int lb   = (bb < nb0) ? bb : bb - nb0;
        const int n    = g ? n1 : n0;
        const int* fl  = g ? flags1 : flags0;
        const int r0   = lb * FB;
        const int nr   = (n - r0 < FB) ? (n - r0) : FB;

        if (tid < FB) {
            int idx = r0 + tid;
            if (idx >= n) idx = n - 1;
            stok[tid] = fl[idx];
        }
        __syncthreads();
        for (int i = tid; i < FB * (HID / 4); i += 320) {
            int r = i >> 7, k4 = i & 127;
            *(float4*)&xs[r][k4 * 4] = *(const float4*)(X + (size_t)stok[r] * HID + k4 * 4);
        }
        __syncthreads();

        {
            const int c = tid;
            if (c < CC) {
                const float* wr = W + (size_t)(g * CC + c) * HID;
                float acc[FB];
#pragma unroll
                for (int r = 0; r < FB; ++r) acc[r] = 0.f;
                for (int k4 = 0; k4 < HID / 4; ++k4) {
                    float4 w4 = *(const float4*)(wr + k4 * 4);
#pragma unroll
                    for (int r = 0; r < FB; ++r) {
                        float4 xv = *(const float4*)&xs[r][k4 * 4];
                        acc[r] = fmaf(xv.x, w4.x, acc[r]);
                        acc[r] = fmaf(xv.y, w4.y, acc[r]);
                        acc[r] = fmaf(xv.z, w4.z, acc[r]);
                        acc[r] = fmaf(xv.w, w4.w, acc[r]);
                    }
                }
                float bias = bq[g * CC + c];
#pragma unroll
                for (int r = 0; r < FB; ++r)
                    vals[r][c] = acc[r] + bias + gum[((size_t)stok[r] * GG + g) * CC + c];
            }
        }
        __syncthreads();

        const int lane = tid & 63;
        const int wv   = tid >> 6;
        if (wv < FB) {
            const int r = wv;
            if (r < nr) {
                float b = -3.0e38f; int bi = 0;
#pragma unroll
                for (int j = 0; j < 5; ++j) {
                    int c = lane + j * 64;
                    float v = vals[r][c];
                    if (v > b || (v == b && c < bi)) { b = v; bi = c; }
                }
#pragma unroll
                for (int m = 32; m; m >>= 1) {
                    float ob = __shfl_xor(b, m, 64);
                    int  obi = __shfl_xor(bi, m, 64);
                    if (ob > b || (ob == b && obi < bi)) { b = ob; bi = obi; }
                }
                int tok = stok[r];
                float2 cvv = *(const float2*)(cv + ((size_t)(g * CC + bi)) * DHALF + lane * 2);
                *(float2*)(out + (size_t)tok * 256 + g * DHALF + lane * 2) = cvv;
            }
        }
        __syncthreads();
    }
}

__global__ __launch_bounds__(256) void perpk(
    const float* __restrict__ meanAcc, float* __restrict__ outp, int ntot)
{
    __shared__ float red0[256];
    __shared__ float red1[256];
    const float invn = 1.f / (float)ntot;
    float h0 = 0.f, h1 = 0.f;
    for (int c = threadIdx.x; c < CC; c += 256) {
        float p0 = meanAcc[c]      * invn;
        float p1 = meanAcc[CC + c] * invn;
        h0 -= p0 * logf(p0 + 1e-7f);
        h1 -= p1 * logf(p1 + 1e-7f);
    }
    red0[threadIdx.x] = h0; red1[threadIdx.x] = h1;
    __syncthreads();
    for (int s = 128; s; s >>= 1) {
        if (threadIdx.x < (unsigned)s) {
            red0[threadIdx.x] += red0[threadIdx.x + s];
            red1[threadIdx.x] += red1[threadIdx.x + s];
        }
        __syncthreads();
    }
    if (threadIdx.x == 0) outp[0] = expf(red0[0]) + expf(red1[0]);
}

extern "C" void kernel_launch(void* const* d_in, const int* in_sizes, int n_in,
                              void* d_out, int out_size, void* d_ws, size_t ws_size,
                              hipStream_t stream) {
    const float* x      = (const float*)d_in[0];
    const float* gumbel = (const float*)d_in[1];
    const float* Wq     = (const float*)d_in[2];
    const float* bq     = (const float*)d_in[3];
    const float* cv     = (const float*)d_in[4];
    float* out = (float*)d_out;

    const int NT = in_sizes[0] / HID;       // 32768 tokens

    char* wsc = (char*)d_ws;
    float* meanAcc = (float*)wsc;                          // 640 f
    int*   cnt     = (int*)(wsc + 2560);                   // 2 ints
    int*   flags0  = (int*)(wsc + 4096);                   // 32768 ints
    int*   flags1  = (int*)(wsc + 135168);                 // 32768 ints
    unsigned short* Wh = (unsigned short*)(wsc + 266240);  // 640*512 f16

    zero_misc<<<1, 256, 0, stream>>>(meanAcc, cnt);
    convert_f16<<<(GC * HID / 8 + 255) / 256, 256, 0, stream>>>(Wq, Wh, GC * HID / 8);

    const int nwg = (NT / 128) * 2;         // 512 blocks = 2 per CU
    fused<<<nwg, 512, 0, stream>>>(x, Wh, bq, gumbel, cv, out,
                                   meanAcc, cnt, flags0, flags1);

    fixup<<<256, 320, 0, stream>>>(x, Wq, bq, gumbel, cv, out, flags0, flags1, cnt);
    perpk<<<1, 256, 0, stream>>>(meanAcc, out + (size_t)out_size - 1, NT);
}

// Round 8
// 123.780 us; speedup vs baseline: 1.2717x; 1.2717x over previous
//
#include <hip/hip_runtime.h>
#include <hip/hip_fp16.h>

#define HID 512
#define GC  640
#define CC  320
#define GG  2
#define DHALF 128
#define MARGIN 0.004f
#define FB 4

typedef __attribute__((ext_vector_type(8))) _Float16 half8;
typedef __attribute__((ext_vector_type(4))) float float4v;

__device__ __forceinline__ void gload16(const void* g, void* l) {
    __builtin_amdgcn_global_load_lds(
        (const __attribute__((address_space(1))) void*)(unsigned long long)g,
        (__attribute__((address_space(3))) void*)(unsigned)(unsigned long long)l,
        16, 0, 0);
}

__global__ __launch_bounds__(256) void zero_misc(float* meanAcc, int* cnt) {
    for (int i = threadIdx.x; i < GC; i += 256) meanAcc[i] = 0.f;
    if (threadIdx.x < 2) cnt[threadIdx.x] = 0;
}

__global__ __launch_bounds__(256) void convert_f16(
    const float* __restrict__ in, unsigned short* __restrict__ out, int n8)
{
    int i = blockIdx.x * 256 + threadIdx.x;
    if (i >= n8) return;
    const float4* p = (const float4*)in + (size_t)i * 2;
    float4 v0 = p[0], v1 = p[1];
    float f[8] = {v0.x, v0.y, v0.z, v0.w, v1.x, v1.y, v1.z, v1.w};
    unsigned r[4];
#pragma unroll
    for (int j = 0; j < 4; ++j) {
        __half2 hh = __float22half2_rn(make_float2(f[2*j], f[2*j+1]));
        r[j] = __builtin_bit_cast(unsigned, hh);
    }
    uint4 o = {r[0], r[1], r[2], r[3]};
    *(uint4*)(out + (size_t)i * 8) = o;
}

// Fused GEMM + softmax-mean + argmax + gather.
// Block: 128 tokens x 320 codes (one group). 8 waves; each owns 16 rows x 320 cols.
// Double-buffered As(8KB)+Bs(20KB), one barrier/step, prefetch-before-compute.
// LDS tiles use XOR involution f(o)=o^(((o>>7)&7)<<4): applied to stage SOURCE
// (chunk) with linear gload_lds dest, and to the read address (rule 21).
__global__ __launch_bounds__(512, 4) void fused(
    const float* __restrict__ X, const unsigned short* __restrict__ Wh,
    const float* __restrict__ bq, const float* __restrict__ gum,
    const float* __restrict__ cv, float* __restrict__ out,
    float* __restrict__ meanAcc, int* __restrict__ cnt,
    int* __restrict__ flags0, int* __restrict__ flags1)
{
    __shared__ __align__(16) unsigned short As[2][4096];    // 2 x 8 KB
    __shared__ __align__(16) unsigned short Bs[2][10240];   // 2 x 20 KB
    __shared__ float bqs[CC];
    __shared__ float smean[CC];

    const int tid  = threadIdx.x;
    const int lane = tid & 63;
    const int wid  = tid >> 6;          // 0..7
    const int lq   = lane & 15;
    const int q    = lane >> 4;

    int bid = blockIdx.x;
    int nwg = gridDim.x;
    int swz = ((nwg & 7) == 0) ? (bid & 7) * (nwg >> 3) + (bid >> 3) : bid;
    const int g    = swz & 1;
    const int tok0 = (swz >> 1) * 128;
    int* flagsg = g ? flags1 : flags0;

    for (int i = tid; i < CC; i += 512) { bqs[i] = bq[g * CC + i]; smean[i] = 0.f; }

    // ---- B staging: 20 issues of 64 chunks (16B) = 320 rows x 4 slots.
    // dest chunk (linear) c = iss*64+lane; source chunk c' = c ^ ((c>>3)&7).
    const int iss0 = wid, iss1 = wid + 8, iss2 = wid + 16;  // iss2 only wid<4
    const int c0 = (iss0 * 64 + lane) ^ (((iss0 * 64 + lane) >> 3) & 7);
    const int c1 = (iss1 * 64 + lane) ^ (((iss1 * 64 + lane) >> 3) & 7);
    const int c2 = (iss2 * 64 + lane) ^ (((iss2 * 64 + lane) >> 3) & 7);
    const unsigned short* srcB0 = Wh + ((size_t)(g * CC + (c0 >> 2))) * HID + (c0 & 3) * 8;
    const unsigned short* srcB1 = Wh + ((size_t)(g * CC + (c1 >> 2))) * HID + (c1 & 3) * 8;
    const unsigned short* srcB2 = Wh + ((size_t)(g * CC + (c2 >> 2))) * HID + (c2 & 3) * 8;

    // ---- A staging: thread t -> dest chunk t (linear write at t*16B);
    // source chunk ca = t ^ ((t>>3)&7): row = ca>>2, slot = ca&3 (fp32, 8 floats).
    const int ca = tid ^ ((tid >> 3) & 7);
    const float* xsrc = X + (size_t)(tok0 + (ca >> 2)) * HID + (ca & 3) * 8;

    // ---- read offsets (bytes, swizzled)
    int aoff = ((wid * 16 + lq) << 6) + (q << 4);
    aoff ^= ((aoff >> 7) & 7) << 4;
    int boff = (lq << 6) + (q << 4);
    boff ^= (((lq >> 1) & 7) << 4);          // j*1024 added later (bits >=10, mask-safe)

    float4v acc[20];
#pragma unroll
    for (int j = 0; j < 20; ++j) acc[j] = (float4v){0.f, 0.f, 0.f, 0.f};

    // ---- prologue: stage k-step 0 into buffer 0
    {
        float4 xa = *(const float4*)xsrc;
        float4 xb = *(const float4*)(xsrc + 4);
        gload16(srcB0, &Bs[0][iss0 * 512]);
        gload16(srcB1, &Bs[0][iss1 * 512]);
        if (wid < 4) gload16(srcB2, &Bs[0][iss2 * 512]);
        half8 h;
        h[0] = (_Float16)xa.x; h[1] = (_Float16)xa.y;
        h[2] = (_Float16)xa.z; h[3] = (_Float16)xa.w;
        h[4] = (_Float16)xb.x; h[5] = (_Float16)xb.y;
        h[6] = (_Float16)xb.z; h[7] = (_Float16)xb.w;
        *(half8*)&As[0][tid * 8] = h;
    }
    __syncthreads();

    int cur = 0;
    for (int kk = 0; kk < 16; ++kk) {
        // prefetch next step (kk=15 wraps to 0: branchless, harmless)
        const int k0n = ((kk + 1) & 15) * 32;
        float4 nxa = *(const float4*)(xsrc + k0n);
        float4 nxb = *(const float4*)(xsrc + k0n + 4);
        gload16(srcB0 + k0n, &Bs[cur ^ 1][iss0 * 512]);
        gload16(srcB1 + k0n, &Bs[cur ^ 1][iss1 * 512]);
        if (wid < 4) gload16(srcB2 + k0n, &Bs[cur ^ 1][iss2 * 512]);

        // compute current step
        half8 a = *(const half8*)((const char*)&As[cur][0] + aoff);
        const char* bbase = (const char*)&Bs[cur][0] + boff;
#pragma unroll
        for (int j = 0; j < 20; ++j) {
            half8 b = *(const half8*)(bbase + j * 1024);
            acc[j] = __builtin_amdgcn_mfma_f32_16x16x32_f16(a, b, acc[j], 0, 0, 0);
        }

        // write next A tile (waits only on nxa/nxb; B gloads older, drain first)
        half8 h;
        h[0] = (_Float16)nxa.x; h[1] = (_Float16)nxa.y;
        h[2] = (_Float16)nxa.z; h[3] = (_Float16)nxa.w;
        h[4] = (_Float16)nxb.x; h[5] = (_Float16)nxb.y;
        h[6] = (_Float16)nxb.z; h[7] = (_Float16)nxb.w;
        *(half8*)&As[cur ^ 1][tid * 8] = h;

        __syncthreads();
        cur ^= 1;
    }

    // ---- epilogue: q-group owns row = wid*16 + q*4 + r; lane lq holds cols j*16+lq.
    float macc[20];
#pragma unroll
    for (int j = 0; j < 20; ++j) macc[j] = 0.f;

#pragma unroll
    for (int r = 0; r < 4; ++r) {
        const int rowL  = wid * 16 + q * 4 + r;
        const int tglob = tok0 + rowL;
        const float* grow = gum + ((size_t)tglob * GG + g) * CC;
        float s = 0.f;
        float b = -3.0e38f; int bi = 0; float s2 = -3.0e38f;
#pragma unroll
        for (int j = 0; j < 20; ++j) {
            const int c = j * 16 + lq;
            float lg = acc[j][r] + bqs[c];
            float v  = lg + grow[c];
            if (v > b)       { s2 = b; b = v; bi = c; }
            else if (v > s2) { s2 = v; }
            s += __expf(lg);
        }
        // fused 4-step reduce within the 16-lane group: sum + (max, idx, second)
#pragma unroll
        for (int m = 1; m < 16; m <<= 1) {
            float os  = __shfl_xor(s,  m, 64);
            float ob  = __shfl_xor(b,  m, 64);
            int   obi = __shfl_xor(bi, m, 64);
            float os2 = __shfl_xor(s2, m, 64);
            s += os;
            if (ob > b || (ob == b && obi < bi)) { s2 = fmaxf(os2, b); b = ob; bi = obi; }
            else                                 { s2 = fmaxf(s2, ob); }
        }
        float inv = 1.f / s;
#pragma unroll
        for (int j = 0; j < 20; ++j)
            macc[j] += __expf(acc[j][r] + bqs[j * 16 + lq]) * inv;

        if (lq == 0 && (b - s2) < MARGIN) {
            int p = atomicAdd(&cnt[g], 1);
            flagsg[p] = tglob;
        }
        const float* cvp = cv + ((size_t)(g * CC + bi)) * DHALF + lq * 8;
        float4 c0v = *(const float4*)cvp;
        float4 c1v = *(const float4*)(cvp + 4);
        float* op = out + (size_t)tglob * 256 + g * DHALF + lq * 8;
        *(float4*)op       = c0v;
        *(float4*)(op + 4) = c1v;
    }
#pragma unroll
    for (int j = 0; j < 20; ++j) {
        macc[j] += __shfl_xor(macc[j], 16, 64);
        macc[j] += __shfl_xor(macc[j], 32, 64);
    }
    if (lane < 16) {
#pragma unroll
        for (int j = 0; j < 20; ++j)
            atomicAdd(&smean[j * 16 + lq], macc[j]);
    }
    __syncthreads();
    for (int i = tid; i < CC; i += 512)
        atomicAdd(&meanAcc[g * CC + i], smean[i]);
}

// Exact fp32 recompute for flagged rows: FB rows share one W pass.
__global__ __launch_bounds__(320) void fixup(
    const float* __restrict__ X, const float* __restrict__ W,
    const float* __restrict__ bq, const float* __restrict__ gum,
    const float* __restrict__ cv, float* __restrict__ out,
    const int* __restrict__ flags0, const int* __restrict__ flags1,
    const int* __restrict__ cnt)
{
    __shared__ float xs[FB][HID];
    __shared__ float vals[FB][CC];
    __shared__ int stok[FB];
    const int tid = threadIdx.x;
    const int n0 = cnt[0], n1 = cnt[1];
    const int nb0 = (n0 + FB - 1) / FB;
    const int nb1 = (n1 + FB - 1) / FB;

    for (int bb = blockIdx.x; bb < nb0 + nb1; bb += gridDim.x) {
        const int g    = (bb < nb0) ? 0 : 1;
        const int lb   = (bb < nb0) ? bb : bb - nb0;
        const int n    = g ? n1 : n0;
        const int* fl  = g ? flags1 : flags0;
        const int r0   = lb * FB;
        const int nr   = (n - r0 < FB) ? (n - r0) : FB;

        if (tid < FB) {
            int idx = r0 + tid;
            if (idx >= n) idx = n - 1;
            stok[tid] = fl[idx];
        }
        __syncthreads();
        for (int i = tid; i < FB * (HID / 4); i += 320) {
            int r = i >> 7, k4 = i & 127;
            *(float4*)&xs[r][k4 * 4] = *(const float4*)(X + (size_t)stok[r] * HID + k4 * 4);
        }
        __syncthreads();

        {
            const int c = tid;
            if (c < CC) {
                const float* wr = W + (size_t)(g * CC + c) * HID;
                float acc[FB];
#pragma unroll
                for (int r = 0; r < FB; ++r) acc[r] = 0.f;
                for (int k4 = 0; k4 < HID / 4; ++k4) {
                    float4 w4 = *(const float4*)(wr + k4 * 4);
#pragma unroll
                    for (int r = 0; r < FB; ++r) {
                        float4 xv = *(const float4*)&xs[r][k4 * 4];
                        acc[r] = fmaf(xv.x, w4.x, acc[r]);
                        acc[r] = fmaf(xv.y, w4.y, acc[r]);
                        acc[r] = fmaf(xv.z, w4.z, acc[r]);
                        acc[r] = fmaf(xv.w, w4.w, acc[r]);
                    }
                }
                float bias = bq[g * CC + c];
#pragma unroll
                for (int r = 0; r < FB; ++r)
                    vals[r][c] = acc[r] + bias + gum[((size_t)stok[r] * GG + g) * CC + c];
            }
        }
        __syncthreads();

        const int lane = tid & 63;
        const int wv   = tid >> 6;
        if (wv < FB) {
            const int r = wv;
            if (r < nr) {
                float b = -3.0e38f; int bi = 0;
#pragma unroll
                for (int j = 0; j < 5; ++j) {
                    int c = lane + j * 64;
                    float v = vals[r][c];
                    if (v > b || (v == b && c < bi)) { b = v; bi = c; }
                }
#pragma unroll
                for (int m = 32; m; m >>= 1) {
                    float ob = __shfl_xor(b, m, 64);
                    int  obi = __shfl_xor(bi, m, 64);
                    if (ob > b || (ob == b && obi < bi)) { b = ob; bi = obi; }
                }
                int tok = stok[r];
                float2 cvv = *(const float2*)(cv + ((size_t)(g * CC + bi)) * DHALF + lane * 2);
                *(float2*)(out + (size_t)tok * 256 + g * DHALF + lane * 2) = cvv;
            }
        }
        __syncthreads();
    }
}

__global__ __launch_bounds__(256) void perpk(
    const float* __restrict__ meanAcc, float* __restrict__ outp, int ntot)
{
    __shared__ float red0[256];
    __shared__ float red1[256];
    const float invn = 1.f / (float)ntot;
    float h0 = 0.f, h1 = 0.f;
    for (int c = threadIdx.x; c < CC; c += 256) {
        float p0 = meanAcc[c]      * invn;
        float p1 = meanAcc[CC + c] * invn;
        h0 -= p0 * logf(p0 + 1e-7f);
        h1 -= p1 * logf(p1 + 1e-7f);
    }
    red0[threadIdx.x] = h0; red1[threadIdx.x] = h1;
    __syncthreads();
    for (int s = 128; s; s >>= 1) {
        if (threadIdx.x < (unsigned)s) {
            red0[threadIdx.x] += red0[threadIdx.x + s];
            red1[threadIdx.x] += red1[threadIdx.x + s];
        }
        __syncthreads();
    }
    if (threadIdx.x == 0) outp[0] = expf(red0[0]) + expf(red1[0]);
}

extern "C" void kernel_launch(void* const* d_in, const int* in_sizes, int n_in,
                              void* d_out, int out_size, void* d_ws, size_t ws_size,
                              hipStream_t stream) {
    const float* x      = (const float*)d_in[0];
    const float* gumbel = (const float*)d_in[1];
    const float* Wq     = (const float*)d_in[2];
    const float* bq     = (const float*)d_in[3];
    const float* cv     = (const float*)d_in[4];
    float* out = (float*)d_out;

    const int NT = in_sizes[0] / HID;       // 32768 tokens

    char* wsc = (char*)d_ws;
    float* meanAcc = (float*)wsc;                          // 640 f
    int*   cnt     = (int*)(wsc + 2560);                   // 2 ints
    int*   flags0  = (int*)(wsc + 4096);                   // 32768 ints
    int*   flags1  = (int*)(wsc + 135168);                 // 32768 ints
    unsigned short* Wh = (unsigned short*)(wsc + 266240);  // 640*512 f16

    zero_misc<<<1, 256, 0, stream>>>(meanAcc, cnt);
    convert_f16<<<(GC * HID / 8 + 255) / 256, 256, 0, stream>>>(Wq, Wh, GC * HID / 8);

    const int nwg = (NT / 128) * 2;         // 512 blocks = 2 per CU
    fused<<<nwg, 512, 0, stream>>>(x, Wh, bq, gumbel, cv, out,
                                   meanAcc, cnt, flags0, flags1);

    fixup<<<256, 320, 0, stream>>>(x, Wq, bq, gumbel, cv, out, flags0, flags1, cnt);
    perpk<<<1, 256, 0, stream>>>(meanAcc, out + (size_t)out_size - 1, NT);
}